// Round 3
// baseline (203.341 us; speedup 1.0000x reference)
//
#include <hip/hip_runtime.h>
#include <hip/hip_bf16.h>

typedef __attribute__((ext_vector_type(4))) float f32x4;
typedef __attribute__((ext_vector_type(8))) short short8;

#define B_   4
#define T_   1024
#define H_   16
#define DK_  64
#define KDIM 1024

// Q pre-scale: 1/sqrt(d_k) * log2(e) so attention works in exp2 domain
#define QSCALE 0.18033688011112042f

__device__ __forceinline__ unsigned short f2bf(float f){
  union { float f; unsigned int u; } a; a.f = f;
  unsigned int u = a.u;
  return (unsigned short)((u + 0x7FFFu + ((u >> 16) & 1u)) >> 16);
}

__device__ __forceinline__ unsigned short f2bf_rn(float f){
  union { __hip_bfloat16 h; unsigned short u; } cv;
  cv.h = __float2bfloat16(f);
  return cv.u;
}

__device__ __forceinline__ void gload16(const void* g, void* l){
  __builtin_amdgcn_global_load_lds(
      (const __attribute__((address_space(1))) unsigned int*)g,
      (__attribute__((address_space(3))) unsigned int*)l,
      16, 0, 0);
}

template<int N> __device__ __forceinline__ void wait_vmcnt(){
  if constexpr (N == 0)      asm volatile("s_waitcnt vmcnt(0)" ::: "memory");
  else if constexpr (N == 4) asm volatile("s_waitcnt vmcnt(4)" ::: "memory");
  else if constexpr (N == 6) asm volatile("s_waitcnt vmcnt(6)" ::: "memory");
}

// ---------------- fp32 -> bf16 conversion of x and the 4 weights ----------------
__global__ __launch_bounds__(256) void convert5(
    const float* __restrict__ x,  const float* __restrict__ wq,
    const float* __restrict__ wk, const float* __restrict__ wv,
    const float* __restrict__ wo,
    short* __restrict__ xb,  short* __restrict__ wqb,
    short* __restrict__ wkb, short* __restrict__ wvb, short* __restrict__ wob)
{
  int i = blockIdx.x * 256 + threadIdx.x;   // over 2M float4 chunks
  const float* s; short* d; int off;
  if (i < (1 << 20)) { s = x; d = xb; off = i; }
  else {
    int j = i - (1 << 20);
    int w = j >> 18;
    off = j & ((1 << 18) - 1);
    s = (w == 0) ? wq : (w == 1) ? wk : (w == 2) ? wv : wo;
    d = (w == 0) ? wqb : (w == 1) ? wkb : (w == 2) ? wvb : wob;
  }
  float4 v = ((const float4*)s)[off];
  ushort4 o;
  o.x = f2bf(v.x); o.y = f2bf(v.y); o.z = f2bf(v.z); o.w = f2bf(v.w);
  ((ushort4*)d)[off] = o;
}

// ---------------- multi-phase GEMM core (T3+T4+T5): C = A @ W^T ----------------
// BMxBN tile, BK=64, 8 waves (WARPS_M=4 x WARPS_N=2), 3 LDS buffers,
// counted vmcnt at K-tile boundaries (loads stay 2 tiles in flight).
template<int BM, int BN>
__device__ __forceinline__ void stage_range(
    const short* __restrict__ A, const short* __restrict__ W,
    int m0, int n0, int kt, int lo, int hi,
    short* Asb, short* Bsb, int wv, int lane)
{
  constexpr int LA = BM / 64, LB = BN / 64;
  const int r8 = lane >> 3, c8 = (lane & 7) * 8;
#pragma unroll
  for (int i = lo; i < hi; ++i) {
    if (i < LA) {
      const int r = (wv * LA + i) * 8 + r8;
      gload16(A + (size_t)(m0 + r) * KDIM + kt * 64 + c8, Asb + (wv * LA + i) * 512);
    } else {
      const int ib = i - LA;
      const int r = (wv * LB + ib) * 8 + r8;
      gload16(W + (size_t)(n0 + r) * KDIM + kt * 64 + c8, Bsb + (wv * LB + ib) * 512);
    }
  }
}

template<int BM, int BN>
__device__ __forceinline__ void gemm8_core(
    const short* __restrict__ A, const short* __restrict__ W,
    int m0, int n0, short* As, short* Bs,
    f32x4 acc[BM / 64][BN / 32])
{
  constexpr int M_REP = BM / 64, N_REP = BN / 32;
  constexpr int LA = BM / 64, LB = BN / 64, L = LA + LB;
  constexpr int NKT = 16;                 // K=1024 / BK=64
  const int tid = threadIdx.x;
  const int wv = tid >> 6, lane = tid & 63;
  const int lr = lane & 15, lq = lane >> 4;
  const int wm = wv >> 1, wn = wv & 1;    // 4x2 wave grid
  const int arow = wm * (BM / 4);
  const int brow = wn * (BN / 2);

#pragma unroll
  for (int m = 0; m < M_REP; ++m)
#pragma unroll
    for (int n = 0; n < N_REP; ++n) acc[m][n] = (f32x4){0.f, 0.f, 0.f, 0.f};

  // prologue: tiles 0 and 1 fully issued (2L loads in flight per thread)
  stage_range<BM, BN>(A, W, m0, n0, 0, 0, L, As,             Bs,             wv, lane);
  stage_range<BM, BN>(A, W, m0, n0, 1, 0, L, As + BM * 64,   Bs + BN * 64,   wv, lane);

  int buf = 0;
  for (int kt = 0; kt < NKT; ++kt) {
    if (kt < NKT - 1) wait_vmcnt<L>(); else wait_vmcnt<0>();
    __builtin_amdgcn_s_barrier();
    const short* Ab = As + buf * (BM * 64);
    const short* Bb = Bs + buf * (BN * 64);
    const int sb = (buf >= 1) ? buf - 1 : 2;     // (kt+2) % 3
    short* Asb = As + sb * (BM * 64);
    short* Bsb = Bs + sb * (BN * 64);
#pragma unroll
    for (int kk = 0; kk < 2; ++kk) {
      short8 af[M_REP], bfv[N_REP];
#pragma unroll
      for (int m = 0; m < M_REP; ++m)
        af[m] = *(const short8*)(Ab + (arow + m * 16 + lr) * 64 + kk * 32 + lq * 8);
#pragma unroll
      for (int n = 0; n < N_REP; ++n)
        bfv[n] = *(const short8*)(Bb + (brow + n * 16 + lr) * 64 + kk * 32 + lq * 8);
      if (kt + 2 < NKT)
        stage_range<BM, BN>(A, W, m0, n0, kt + 2, kk * (L / 2), (kk + 1) * (L / 2),
                            Asb, Bsb, wv, lane);
      __builtin_amdgcn_s_barrier();
      __builtin_amdgcn_s_setprio(1);
#pragma unroll
      for (int m = 0; m < M_REP; ++m)
#pragma unroll
        for (int n = 0; n < N_REP; ++n)
          acc[m][n] = __builtin_amdgcn_mfma_f32_16x16x32_bf16(af[m], bfv[n], acc[m][n], 0, 0, 0);
      __builtin_amdgcn_s_setprio(0);
      __builtin_amdgcn_sched_barrier(0);
      __builtin_amdgcn_s_barrier();
    }
    buf = (buf == 2) ? 0 : buf + 1;
  }
}

// ---------------- fused QKV projection (BM=256, BN=128) ----------------
// 1-D grid 384 blocks, XCD-swizzled. wsel: 0=Q,1=K,2=V(transposed store).
__global__ __launch_bounds__(512, 2) void gemm8_qkv(
    const short* __restrict__ xb,
    const short* __restrict__ Wqb, const short* __restrict__ Wkb, const short* __restrict__ Wvb,
    short* __restrict__ Qb, short* __restrict__ Kb, short* __restrict__ VTb)
{
  __shared__ __align__(16) short As[3 * 256 * 64];
  __shared__ __align__(16) short Bs[3 * 128 * 64];
  const int bid = blockIdx.x;
  const int wgid = (bid & 7) * 48 + (bid >> 3);   // T1 bijective (384 % 8 == 0)
  const int mx = wgid & 15, nyy = wgid >> 4;      // ny-major chunks share W-panels
  const int wsel = nyy >> 3;
  const int m0 = mx * 256, n0 = (nyy & 7) * 128;
  const short* W = (wsel == 0) ? Wqb : (wsel == 1) ? Wkb : Wvb;

  f32x4 acc[4][4];
  gemm8_core<256, 128>(xb, W, m0, n0, As, Bs, acc);

  const int tid = threadIdx.x, lane = tid & 63, wv = tid >> 6;
  const int lr = lane & 15, lq = lane >> 4, wm = wv >> 1, wn = wv & 1;
  if (wsel < 2) {
    short* O = wsel ? Kb : Qb;
    const float sc = wsel ? 1.0f : QSCALE;
#pragma unroll
    for (int m = 0; m < 4; ++m)
#pragma unroll
      for (int n = 0; n < 4; ++n)
#pragma unroll
        for (int j = 0; j < 4; ++j) {
          int row = m0 + wm * 64 + m * 16 + lq * 4 + j;
          int col = n0 + wn * 64 + n * 16 + lr;
          O[(size_t)row * KDIM + col] = (short)f2bf(acc[m][n][j] * sc);
        }
  } else {
#pragma unroll
    for (int m = 0; m < 4; ++m)
#pragma unroll
      for (int n = 0; n < 4; ++n) {
        int row = m0 + wm * 64 + m * 16 + lq * 4;
        int col = n0 + wn * 64 + n * 16 + lr;
        int b = row >> 10, t = row & 1023, h = col >> 6, d = col & 63;
        ushort4 v;
        v.x = f2bf(acc[m][n][0]); v.y = f2bf(acc[m][n][1]);
        v.z = f2bf(acc[m][n][2]); v.w = f2bf(acc[m][n][3]);
        *(ushort4*)&VTb[(size_t)((b * 16 + h) * 64 + d) * 1024 + t] = v;
      }
  }
}

// ---------------- output projection + bias (BM=128, BN=128, fp32 out) ----------------
__global__ __launch_bounds__(512, 2) void gemm8_out(
    const short* __restrict__ AOb, const short* __restrict__ Wob,
    const float* __restrict__ bias, float* __restrict__ out)
{
  __shared__ __align__(16) short As[3 * 128 * 64];
  __shared__ __align__(16) short Bs[3 * 128 * 64];
  const int bid = blockIdx.x;
  const int wgid = (bid & 7) * 32 + (bid >> 3);   // 256 % 8 == 0
  const int mx = wgid & 31, ny = wgid >> 5;
  const int m0 = mx * 128, n0 = ny * 128;

  f32x4 acc[2][4];
  gemm8_core<128, 128>(AOb, Wob, m0, n0, As, Bs, acc);

  const int tid = threadIdx.x, lane = tid & 63, wv = tid >> 6;
  const int lr = lane & 15, lq = lane >> 4, wm = wv >> 1, wn = wv & 1;
#pragma unroll
  for (int m = 0; m < 2; ++m)
#pragma unroll
    for (int n = 0; n < 4; ++n) {
      int col = n0 + wn * 64 + n * 16 + lr;
      float bv = bias[col];
#pragma unroll
      for (int j = 0; j < 4; ++j) {
        int row = m0 + wm * 32 + m * 16 + lq * 4 + j;
        out[(size_t)row * KDIM + col] = acc[m][n][j] + bv;
      }
    }
}

// ---------------- flash attention, swapped-operand form, KVBLK=64 ----------------
// grid (16, 64): x = q-tile of 64 rows, y = b*16+h. 4 waves, 16 q-rows each.
// LDS 40KB -> 4 blocks/CU.
__global__ __launch_bounds__(256) void attn_kern(
    const short* __restrict__ Qb, const short* __restrict__ Kb,
    const short* __restrict__ VTb, short* __restrict__ AOb)
{
  __shared__ __align__(16) short kl[2][64 * 64];   // [kv][d], XOR-swizzled cols
  __shared__ __align__(16) short vl[2][64 * 64];   // [d][kv], XOR-swizzled cols
  __shared__ __align__(16) short pl[4][16 * 64];   // per-wave P [q][kv]
  const int bh = blockIdx.y, b = bh >> 4, h = bh & 15;
  const int q0 = blockIdx.x * 64;
  const int tid = threadIdx.x, wv = tid >> 6, lane = tid & 63;
  const int lr = lane & 15, lq = lane >> 4;

  const short* Qrow = Qb + (size_t)(b * T_ + q0 + wv * 16 + lr) * KDIM + h * DK_;
  short8 qf0 = *(const short8*)(Qrow + lq * 8);
  short8 qf1 = *(const short8*)(Qrow + 32 + lq * 8);

  const short* Kbase = Kb + (size_t)(b * T_) * KDIM + h * DK_;
  const short* Vbase = VTb + (size_t)(bh * DK_) * 1024;

  const int srow = tid >> 3, scol = (tid & 7) * 8;   // staging: 32 rows x 64 cols/round

  auto stage = [&](int buf, int kv0) {
#pragma unroll
    for (int p = 0; p < 2; ++p) {
      const int r = p * 32 + srow;
      gload16(Kbase + (size_t)(kv0 + r) * KDIM + (scol ^ ((r & 7) << 3)),
              &kl[buf][p * 2048 + wv * 512]);
    }
#pragma unroll
    for (int p = 0; p < 2; ++p) {
      const int r = p * 32 + srow;
      gload16(Vbase + (size_t)r * 1024 + kv0 + (scol ^ ((r & 7) << 3)),
              &vl[buf][p * 2048 + wv * 512]);
    }
  };

  f32x4 oacc[4];
#pragma unroll
  for (int i = 0; i < 4; ++i) oacc[i] = (f32x4){0.f, 0.f, 0.f, 0.f};
  float m_r = -1e30f, l_r = 0.f;
  const int swq = (lr & 7) << 3;
  short* plw = pl[wv];

  int cur = 0;
  stage(0, 0);
  __syncthreads();

  for (int kt = 0; kt < 16; ++kt) {
    if (kt < 15) stage(cur ^ 1, (kt + 1) * 64);

    // ---- S^T[kv][q] = K Q^T (4 kv-subtiles x 2 d-chunks) ----
    f32x4 s[4];
#pragma unroll
    for (int nt = 0; nt < 4; ++nt) {
      const int kr = nt * 16 + lr;
      const int sw = (kr & 7) << 3;
      short8 kf0 = *(const short8*)&kl[cur][kr * 64 + ((lq * 8) ^ sw)];
      short8 kf1 = *(const short8*)&kl[cur][kr * 64 + ((32 + lq * 8) ^ sw)];
      f32x4 z = (f32x4){0.f, 0.f, 0.f, 0.f};
      z = __builtin_amdgcn_mfma_f32_16x16x32_bf16(kf0, qf0, z, 0, 0, 0);
      s[nt] = __builtin_amdgcn_mfma_f32_16x16x32_bf16(kf1, qf1, s[nt] = z, 0, 0, 0);
    }

    // ---- online softmax, row q = lr, 16 values in-lane + 2 shfl ----
    float mx;
    {
      float a0 = fmaxf(fmaxf(s[0][0], s[0][1]), fmaxf(s[0][2], s[0][3]));
      float a1 = fmaxf(fmaxf(s[1][0], s[1][1]), fmaxf(s[1][2], s[1][3]));
      float a2 = fmaxf(fmaxf(s[2][0], s[2][1]), fmaxf(s[2][2], s[2][3]));
      float a3 = fmaxf(fmaxf(s[3][0], s[3][1]), fmaxf(s[3][2], s[3][3]));
      mx = fmaxf(fmaxf(a0, a1), fmaxf(a2, a3));
    }
    mx = fmaxf(mx, __shfl_xor(mx, 16));
    mx = fmaxf(mx, __shfl_xor(mx, 32));
    if (!__all(mx <= m_r + 8.f)) {           // defer-max (T13), log2 domain
      const float mn = fmaxf(m_r, mx);
      const float al = exp2f(m_r - mn);
      l_r *= al;
#pragma unroll
      for (int nt = 0; nt < 4; ++nt)
#pragma unroll
        for (int j = 0; j < 4; ++j) oacc[nt][j] *= al;
      m_r = mn;
    }
    float rs = 0.f;
#pragma unroll
    for (int nt = 0; nt < 4; ++nt)
#pragma unroll
      for (int j = 0; j < 4; ++j) {
        float e = exp2f(s[nt][j] - m_r);
        s[nt][j] = e;
        rs += e;
      }
    rs += __shfl_xor(rs, 16);
    rs += __shfl_xor(rs, 32);
    l_r += rs;

    // ---- P -> per-wave LDS (bf16), wave-local fence, PV ----
#pragma unroll
    for (int nt = 0; nt < 4; ++nt) {
      f32x4 v = s[nt];
      ushort4 u;
      u.x = f2bf_rn(v[0]); u.y = f2bf_rn(v[1]);
      u.z = f2bf_rn(v[2]); u.w = f2bf_rn(v[3]);
      *(ushort4*)&plw[lr * 64 + ((nt * 16 + lq * 4) ^ swq)] = u;
    }
    asm volatile("s_waitcnt lgkmcnt(0)" ::: "memory");
    short8 pf0 = *(const short8*)&plw[lr * 64 + ((lq * 8) ^ swq)];
    short8 pf1 = *(const short8*)&plw[lr * 64 + ((32 + lq * 8) ^ swq)];
#pragma unroll
    for (int ntd = 0; ntd < 4; ++ntd) {
      const int vr = ntd * 16 + lr;
      const int sw = (vr & 7) << 3;
      short8 vf0 = *(const short8*)&vl[cur][vr * 64 + ((lq * 8) ^ sw)];
      short8 vf1 = *(const short8*)&vl[cur][vr * 64 + ((32 + lq * 8) ^ sw)];
      oacc[ntd] = __builtin_amdgcn_mfma_f32_16x16x32_bf16(vf0, pf0, oacc[ntd], 0, 0, 0);
      oacc[ntd] = __builtin_amdgcn_mfma_f32_16x16x32_bf16(vf1, pf1, oacc[ntd], 0, 0, 0);
    }
    __syncthreads();
    cur ^= 1;
  }

  // epilogue: O^T[d][q=lr] -> AOb[q][h*64+d]
  const float inv = 1.0f / l_r;
#pragma unroll
  for (int nt = 0; nt < 4; ++nt) {
    ushort4 u;
    u.x = f2bf_rn(oacc[nt][0] * inv);
    u.y = f2bf_rn(oacc[nt][1] * inv);
    u.z = f2bf_rn(oacc[nt][2] * inv);
    u.w = f2bf_rn(oacc[nt][3] * inv);
    *(ushort4*)&AOb[(size_t)(b * T_ + q0 + wv * 16 + lr) * KDIM + h * DK_ + nt * 16 + lq * 4] = u;
  }
}

extern "C" void kernel_launch(void* const* d_in, const int* in_sizes, int n_in,
                              void* d_out, int out_size, void* d_ws, size_t ws_size,
                              hipStream_t stream) {
  const float* x  = (const float*)d_in[0];
  const float* Wq = (const float*)d_in[1];
  const float* Wk = (const float*)d_in[2];
  const float* Wv = (const float*)d_in[3];
  const float* Wo = (const float*)d_in[4];
  const float* bo = (const float*)d_in[5];

  short* ws = (short*)d_ws;
  short* xb  = ws;
  short* Wqb = ws + 4194304;
  short* Wkb = ws + 5242880;
  short* Wvb = ws + 6291456;
  short* Wob = ws + 7340032;
  short* Qb  = ws + 8388608;
  short* Kb  = ws + 12582912;
  short* VTb = ws + 16777216;
  short* AOb = ws + 20971520;

  convert5<<<8192, 256, 0, stream>>>(x, Wq, Wk, Wv, Wo, xb, Wqb, Wkb, Wvb, Wob);
  gemm8_qkv<<<384, 512, 0, stream>>>(xb, Wqb, Wkb, Wvb, Qb, Kb, VTb);
  attn_kern<<<dim3(16, 64), 256, 0, stream>>>(Qb, Kb, VTb, AOb);
  gemm8_out<<<256, 512, 0, stream>>>(AOb, Wob, bo, (float*)d_out);
}

// Round 4
// 181.763 us; speedup vs baseline: 1.1187x; 1.1187x over previous
//
#include <hip/hip_runtime.h>
#include <hip/hip_bf16.h>

typedef __attribute__((ext_vector_type(4))) float f32x4;
typedef __attribute__((ext_vector_type(8))) short short8;

#define B_   4
#define T_   1024
#define H_   16
#define DK_  64
#define KDIM 1024

// Q pre-scale: 1/sqrt(d_k) * log2(e) so attention works in exp2 domain
#define QSCALE 0.18033688011112042f

__device__ __forceinline__ unsigned short f2bf(float f){
  union { float f; unsigned int u; } a; a.f = f;
  unsigned int u = a.u;
  return (unsigned short)((u + 0x7FFFu + ((u >> 16) & 1u)) >> 16);
}

__device__ __forceinline__ unsigned short f2bf_rn(float f){
  union { __hip_bfloat16 h; unsigned short u; } cv;
  cv.h = __float2bfloat16(f);
  return cv.u;
}

__device__ __forceinline__ void gload16(const void* g, void* l){
  __builtin_amdgcn_global_load_lds(
      (const __attribute__((address_space(1))) unsigned int*)g,
      (__attribute__((address_space(3))) unsigned int*)l,
      16, 0, 0);
}

template<int N> __device__ __forceinline__ void wait_vmcnt(){
  if constexpr (N == 0)      asm volatile("s_waitcnt vmcnt(0)" ::: "memory");
  else if constexpr (N == 4) asm volatile("s_waitcnt vmcnt(4)" ::: "memory");
  else if constexpr (N == 6) asm volatile("s_waitcnt vmcnt(6)" ::: "memory");
}

// ---------------- fp32 -> bf16 conversion of x and the 4 weights ----------------
__global__ __launch_bounds__(256) void convert5(
    const float* __restrict__ x,  const float* __restrict__ wq,
    const float* __restrict__ wk, const float* __restrict__ wv,
    const float* __restrict__ wo,
    short* __restrict__ xb,  short* __restrict__ wqb,
    short* __restrict__ wkb, short* __restrict__ wvb, short* __restrict__ wob)
{
  int i = blockIdx.x * 256 + threadIdx.x;   // over 2M float4 chunks
  const float* s; short* d; int off;
  if (i < (1 << 20)) { s = x; d = xb; off = i; }
  else {
    int j = i - (1 << 20);
    int w = j >> 18;
    off = j & ((1 << 18) - 1);
    s = (w == 0) ? wq : (w == 1) ? wk : (w == 2) ? wv : wo;
    d = (w == 0) ? wqb : (w == 1) ? wkb : (w == 2) ? wvb : wob;
  }
  float4 v = ((const float4*)s)[off];
  ushort4 o;
  o.x = f2bf(v.x); o.y = f2bf(v.y); o.z = f2bf(v.z); o.w = f2bf(v.w);
  ((ushort4*)d)[off] = o;
}

// ---------------- multi-phase GEMM core (T2+T3+T4+T5): C = A @ W^T ----------------
// BMxBN tile, BK=64, 8 waves (4x2), 3 LDS buffers, counted vmcnt at K-tile
// boundaries. LDS rows of 64 bf16 (128B) XOR-swizzled at 16B granularity:
// slot ^= (row&7). Staging pre-swizzles the GLOBAL source col (linear LDS dest,
// rule #21); fragment reads apply the same XOR.
template<int BM, int BN>
__device__ __forceinline__ void stage_range(
    const short* __restrict__ A, const short* __restrict__ W,
    int m0, int n0, int kt, int lo, int hi,
    short* Asb, short* Bsb, int wv, int lane)
{
  constexpr int LA = BM / 64, LB = BN / 64;
  const int r8 = lane >> 3;
  const int c8 = ((lane & 7) * 8) ^ (r8 * 8);   // pre-swizzled source col
#pragma unroll
  for (int i = lo; i < hi; ++i) {
    if (i < LA) {
      const int r = (wv * LA + i) * 8 + r8;
      gload16(A + (size_t)(m0 + r) * KDIM + kt * 64 + c8, Asb + (wv * LA + i) * 512);
    } else {
      const int ib = i - LA;
      const int r = (wv * LB + ib) * 8 + r8;
      gload16(W + (size_t)(n0 + r) * KDIM + kt * 64 + c8, Bsb + (wv * LB + ib) * 512);
    }
  }
}

template<int BM, int BN>
__device__ __forceinline__ void gemm8_core(
    const short* __restrict__ A, const short* __restrict__ W,
    int m0, int n0, short* As, short* Bs,
    f32x4 acc[BM / 64][BN / 32])
{
  constexpr int M_REP = BM / 64, N_REP = BN / 32;
  constexpr int LA = BM / 64, LB = BN / 64, L = LA + LB;
  constexpr int NKT = 16;                 // K=1024 / BK=64
  const int tid = threadIdx.x;
  const int wv = tid >> 6, lane = tid & 63;
  const int lr = lane & 15, lq = lane >> 4;
  const int wm = wv >> 1, wn = wv & 1;    // 4x2 wave grid
  const int arow = wm * (BM / 4);
  const int brow = wn * (BN / 2);
  const int swz = (lr & 7) << 3;          // read-side XOR (row&7 == lr&7 here)

#pragma unroll
  for (int m = 0; m < M_REP; ++m)
#pragma unroll
    for (int n = 0; n < N_REP; ++n) acc[m][n] = (f32x4){0.f, 0.f, 0.f, 0.f};

  // prologue: tiles 0 and 1 fully issued (2L loads in flight per thread)
  stage_range<BM, BN>(A, W, m0, n0, 0, 0, L, As,           Bs,           wv, lane);
  stage_range<BM, BN>(A, W, m0, n0, 1, 0, L, As + BM * 64, Bs + BN * 64, wv, lane);

  int buf = 0;
  for (int kt = 0; kt < NKT; ++kt) {
    if (kt < NKT - 1) wait_vmcnt<L>(); else wait_vmcnt<0>();
    __builtin_amdgcn_s_barrier();
    const short* Ab = As + buf * (BM * 64);
    const short* Bb = Bs + buf * (BN * 64);
    const int sb = (buf >= 1) ? buf - 1 : 2;     // (kt+2) % 3
    short* Asb = As + sb * (BM * 64);
    short* Bsb = Bs + sb * (BN * 64);
#pragma unroll
    for (int kk = 0; kk < 2; ++kk) {
      short8 af[M_REP], bfv[N_REP];
#pragma unroll
      for (int m = 0; m < M_REP; ++m)
        af[m] = *(const short8*)(Ab + (arow + m * 16 + lr) * 64 + ((kk * 32 + lq * 8) ^ swz));
#pragma unroll
      for (int n = 0; n < N_REP; ++n)
        bfv[n] = *(const short8*)(Bb + (brow + n * 16 + lr) * 64 + ((kk * 32 + lq * 8) ^ swz));
      if (kt + 2 < NKT)
        stage_range<BM, BN>(A, W, m0, n0, kt + 2, kk * (L / 2), (kk + 1) * (L / 2),
                            Asb, Bsb, wv, lane);
      __builtin_amdgcn_s_barrier();
      __builtin_amdgcn_s_setprio(1);
#pragma unroll
      for (int m = 0; m < M_REP; ++m)
#pragma unroll
        for (int n = 0; n < N_REP; ++n)
          acc[m][n] = __builtin_amdgcn_mfma_f32_16x16x32_bf16(af[m], bfv[n], acc[m][n], 0, 0, 0);
      __builtin_amdgcn_s_setprio(0);
      __builtin_amdgcn_sched_barrier(0);
      __builtin_amdgcn_s_barrier();
    }
    buf = (buf == 2) ? 0 : buf + 1;
  }
}

// ---------------- fused QKV projection (BM=256, BN=128) ----------------
// 384 blocks, XCD-chunked; within an XCD chunk, n-major (2 x-panels/XCD fit L2).
__global__ __launch_bounds__(512, 2) void gemm8_qkv(
    const short* __restrict__ xb,
    const short* __restrict__ Wqb, const short* __restrict__ Wkb, const short* __restrict__ Wvb,
    short* __restrict__ Qb, short* __restrict__ Kb, short* __restrict__ VTb)
{
  __shared__ __align__(16) short As[3 * 256 * 64];
  __shared__ __align__(16) short Bs[3 * 128 * 64];
  const int bid = blockIdx.x;
  const int wgid = (bid & 7) * 48 + (bid >> 3);   // T1 bijective (384 % 8 == 0)
  const int mx = wgid / 24, nyy = wgid % 24;      // n-major within XCD chunk
  const int wsel = nyy >> 3;
  const int m0 = mx * 256, n0 = (nyy & 7) * 128;
  const short* W = (wsel == 0) ? Wqb : (wsel == 1) ? Wkb : Wvb;

  f32x4 acc[4][4];
  gemm8_core<256, 128>(xb, W, m0, n0, As, Bs, acc);

  const int tid = threadIdx.x, lane = tid & 63, wv = tid >> 6;
  const int lr = lane & 15, lq = lane >> 4, wm = wv >> 1, wn = wv & 1;
  if (wsel < 2) {
    short* O = wsel ? Kb : Qb;
    const float sc = wsel ? 1.0f : QSCALE;
#pragma unroll
    for (int m = 0; m < 4; ++m)
#pragma unroll
      for (int n = 0; n < 4; ++n)
#pragma unroll
        for (int j = 0; j < 4; ++j) {
          int row = m0 + wm * 64 + m * 16 + lq * 4 + j;
          int col = n0 + wn * 64 + n * 16 + lr;
          O[(size_t)row * KDIM + col] = (short)f2bf(acc[m][n][j] * sc);
        }
  } else {
#pragma unroll
    for (int m = 0; m < 4; ++m)
#pragma unroll
      for (int n = 0; n < 4; ++n) {
        int row = m0 + wm * 64 + m * 16 + lq * 4;
        int col = n0 + wn * 64 + n * 16 + lr;
        int b = row >> 10, t = row & 1023, h = col >> 6, d = col & 63;
        ushort4 v;
        v.x = f2bf(acc[m][n][0]); v.y = f2bf(acc[m][n][1]);
        v.z = f2bf(acc[m][n][2]); v.w = f2bf(acc[m][n][3]);
        *(ushort4*)&VTb[(size_t)((b * 16 + h) * 64 + d) * 1024 + t] = v;
      }
  }
}

// ---------------- output projection + bias (BM=128, BN=128, fp32 out) ----------------
__global__ __launch_bounds__(512, 2) void gemm8_out(
    const short* __restrict__ AOb, const short* __restrict__ Wob,
    const float* __restrict__ bias, float* __restrict__ out)
{
  __shared__ __align__(16) short As[3 * 128 * 64];
  __shared__ __align__(16) short Bs[3 * 128 * 64];
  const int bid = blockIdx.x;
  const int wgid = (bid & 7) * 32 + (bid >> 3);   // 256 % 8 == 0
  const int mx = wgid >> 3, ny = wgid & 7;        // n-major within XCD chunk
  const int m0 = mx * 128, n0 = ny * 128;

  f32x4 acc[2][4];
  gemm8_core<128, 128>(AOb, Wob, m0, n0, As, Bs, acc);

  const int tid = threadIdx.x, lane = tid & 63, wv = tid >> 6;
  const int lr = lane & 15, lq = lane >> 4, wm = wv >> 1, wn = wv & 1;
#pragma unroll
  for (int m = 0; m < 2; ++m)
#pragma unroll
    for (int n = 0; n < 4; ++n) {
      int col = n0 + wn * 64 + n * 16 + lr;
      float bv = bias[col];
#pragma unroll
      for (int j = 0; j < 4; ++j) {
        int row = m0 + wm * 32 + m * 16 + lq * 4 + j;
        out[(size_t)row * KDIM + col] = acc[m][n][j] + bv;
      }
    }
}

// ---------------- flash attention, swapped-operand form, KVBLK=64 ----------------
__global__ __launch_bounds__(256) void attn_kern(
    const short* __restrict__ Qb, const short* __restrict__ Kb,
    const short* __restrict__ VTb, short* __restrict__ AOb)
{
  __shared__ __align__(16) short kl[2][64 * 64];   // [kv][d], XOR-swizzled cols
  __shared__ __align__(16) short vl[2][64 * 64];   // [d][kv], XOR-swizzled cols
  __shared__ __align__(16) short pl[4][16 * 64];   // per-wave P [q][kv]
  const int bh = blockIdx.y, b = bh >> 4, h = bh & 15;
  const int q0 = blockIdx.x * 64;
  const int tid = threadIdx.x, wv = tid >> 6, lane = tid & 63;
  const int lr = lane & 15, lq = lane >> 4;

  const short* Qrow = Qb + (size_t)(b * T_ + q0 + wv * 16 + lr) * KDIM + h * DK_;
  short8 qf0 = *(const short8*)(Qrow + lq * 8);
  short8 qf1 = *(const short8*)(Qrow + 32 + lq * 8);

  const short* Kbase = Kb + (size_t)(b * T_) * KDIM + h * DK_;
  const short* Vbase = VTb + (size_t)(bh * DK_) * 1024;

  const int srow = tid >> 3, scol = (tid & 7) * 8;

  auto stage = [&](int buf, int kv0) {
#pragma unroll
    for (int p = 0; p < 2; ++p) {
      const int r = p * 32 + srow;
      gload16(Kbase + (size_t)(kv0 + r) * KDIM + (scol ^ ((r & 7) << 3)),
              &kl[buf][p * 2048 + wv * 512]);
    }
#pragma unroll
    for (int p = 0; p < 2; ++p) {
      const int r = p * 32 + srow;
      gload16(Vbase + (size_t)r * 1024 + kv0 + (scol ^ ((r & 7) << 3)),
              &vl[buf][p * 2048 + wv * 512]);
    }
  };

  f32x4 oacc[4];
#pragma unroll
  for (int i = 0; i < 4; ++i) oacc[i] = (f32x4){0.f, 0.f, 0.f, 0.f};
  float m_r = -1e30f, l_r = 0.f;
  const int swq = (lr & 7) << 3;
  short* plw = pl[wv];

  int cur = 0;
  stage(0, 0);
  __syncthreads();

  for (int kt = 0; kt < 16; ++kt) {
    if (kt < 15) stage(cur ^ 1, (kt + 1) * 64);

    // ---- S^T[kv][q] = K Q^T ----
    f32x4 s[4];
#pragma unroll
    for (int nt = 0; nt < 4; ++nt) {
      const int kr = nt * 16 + lr;
      const int sw = (kr & 7) << 3;
      short8 kf0 = *(const short8*)&kl[cur][kr * 64 + ((lq * 8) ^ sw)];
      short8 kf1 = *(const short8*)&kl[cur][kr * 64 + ((32 + lq * 8) ^ sw)];
      f32x4 z = (f32x4){0.f, 0.f, 0.f, 0.f};
      z = __builtin_amdgcn_mfma_f32_16x16x32_bf16(kf0, qf0, z, 0, 0, 0);
      s[nt] = __builtin_amdgcn_mfma_f32_16x16x32_bf16(kf1, qf1, z, 0, 0, 0);
    }

    // ---- online softmax, row q = lr ----
    float mx;
    {
      float a0 = fmaxf(fmaxf(s[0][0], s[0][1]), fmaxf(s[0][2], s[0][3]));
      float a1 = fmaxf(fmaxf(s[1][0], s[1][1]), fmaxf(s[1][2], s[1][3]));
      float a2 = fmaxf(fmaxf(s[2][0], s[2][1]), fmaxf(s[2][2], s[2][3]));
      float a3 = fmaxf(fmaxf(s[3][0], s[3][1]), fmaxf(s[3][2], s[3][3]));
      mx = fmaxf(fmaxf(a0, a1), fmaxf(a2, a3));
    }
    mx = fmaxf(mx, __shfl_xor(mx, 16));
    mx = fmaxf(mx, __shfl_xor(mx, 32));
    if (!__all(mx <= m_r + 8.f)) {           // defer-max (T13), log2 domain
      const float mn = fmaxf(m_r, mx);
      const float al = exp2f(m_r - mn);
      l_r *= al;
#pragma unroll
      for (int nt = 0; nt < 4; ++nt)
#pragma unroll
        for (int j = 0; j < 4; ++j) oacc[nt][j] *= al;
      m_r = mn;
    }
    float rs = 0.f;
#pragma unroll
    for (int nt = 0; nt < 4; ++nt)
#pragma unroll
      for (int j = 0; j < 4; ++j) {
        float e = exp2f(s[nt][j] - m_r);
        s[nt][j] = e;
        rs += e;
      }
    rs += __shfl_xor(rs, 16);
    rs += __shfl_xor(rs, 32);
    l_r += rs;

    // ---- P -> per-wave LDS (bf16), wave-local fence, PV ----
#pragma unroll
    for (int nt = 0; nt < 4; ++nt) {
      f32x4 v = s[nt];
      ushort4 u;
      u.x = f2bf_rn(v[0]); u.y = f2bf_rn(v[1]);
      u.z = f2bf_rn(v[2]); u.w = f2bf_rn(v[3]);
      *(ushort4*)&plw[lr * 64 + ((nt * 16 + lq * 4) ^ swq)] = u;
    }
    asm volatile("s_waitcnt lgkmcnt(0)" ::: "memory");
    short8 pf0 = *(const short8*)&plw[lr * 64 + ((lq * 8) ^ swq)];
    short8 pf1 = *(const short8*)&plw[lr * 64 + ((32 + lq * 8) ^ swq)];
#pragma unroll
    for (int ntd = 0; ntd < 4; ++ntd) {
      const int vr = ntd * 16 + lr;
      const int sw = (vr & 7) << 3;
      short8 vf0 = *(const short8*)&vl[cur][vr * 64 + ((lq * 8) ^ sw)];
      short8 vf1 = *(const short8*)&vl[cur][vr * 64 + ((32 + lq * 8) ^ sw)];
      oacc[ntd] = __builtin_amdgcn_mfma_f32_16x16x32_bf16(vf0, pf0, oacc[ntd], 0, 0, 0);
      oacc[ntd] = __builtin_amdgcn_mfma_f32_16x16x32_bf16(vf1, pf1, oacc[ntd], 0, 0, 0);
    }
    __syncthreads();
    cur ^= 1;
  }

  // epilogue: O^T[d][q=lr] -> AOb[q][h*64+d]
  const float inv = 1.0f / l_r;
#pragma unroll
  for (int nt = 0; nt < 4; ++nt) {
    ushort4 u;
    u.x = f2bf_rn(oacc[nt][0] * inv);
    u.y = f2bf_rn(oacc[nt][1] * inv);
    u.z = f2bf_rn(oacc[nt][2] * inv);
    u.w = f2bf_rn(oacc[nt][3] * inv);
    *(ushort4*)&AOb[(size_t)(b * T_ + q0 + wv * 16 + lr) * KDIM + h * DK_ + nt * 16 + lq * 4] = u;
  }
}

extern "C" void kernel_launch(void* const* d_in, const int* in_sizes, int n_in,
                              void* d_out, int out_size, void* d_ws, size_t ws_size,
                              hipStream_t stream) {
  const float* x  = (const float*)d_in[0];
  const float* Wq = (const float*)d_in[1];
  const float* Wk = (const float*)d_in[2];
  const float* Wv = (const float*)d_in[3];
  const float* Wo = (const float*)d_in[4];
  const float* bo = (const float*)d_in[5];

  short* ws = (short*)d_ws;
  short* xb  = ws;
  short* Wqb = ws + 4194304;
  short* Wkb = ws + 5242880;
  short* Wvb = ws + 6291456;
  short* Wob = ws + 7340032;
  short* Qb  = ws + 8388608;
  short* Kb  = ws + 12582912;
  short* VTb = ws + 16777216;
  short* AOb = ws + 20971520;

  convert5<<<8192, 256, 0, stream>>>(x, Wq, Wk, Wv, Wo, xb, Wqb, Wkb, Wvb, Wob);
  gemm8_qkv<<<384, 512, 0, stream>>>(xb, Wqb, Wkb, Wvb, Qb, Kb, VTb);
  attn_kern<<<dim3(16, 64), 256, 0, stream>>>(Qb, Kb, VTb, AOb);
  gemm8_out<<<256, 512, 0, stream>>>(AOb, Wob, bo, (float*)d_out);
}